// Round 8
// baseline (402.317 us; speedup 1.0000x reference)
//
#include <hip/hip_runtime.h>
#include <cstdint>

#define L_DIM 2048
#define B_DIM 16
#define D_DIM 1024
#define M_DIM (L_DIM*B_DIM)   // 32768
#define N_DIM (3*D_DIM)       // 3072
#define K_DIM D_DIM           // 1024
#define NCH   (B_DIM*D_DIM)   // 16384 channels
#define SEG   64
#define SEGLEN (L_DIM/SEG)    // 32
#define CG    (NCH/8)         // 2048 channel-groups of 8

#define BM 128
#define BN 256
#define BK 32
#define NKT (K_DIM/BK)        // 32
#define ABY (BM*BK*2)         // 8192
#define BBY (BN*BK*2)         // 16384
#define BUFB (ABY+BBY)        // 24576 bytes per buffer; x2 = 48 KiB

typedef __bf16 bf16x8 __attribute__((ext_vector_type(8)));
typedef float f32x4 __attribute__((ext_vector_type(4)));

__device__ inline float bf2f(ushort u){ return __uint_as_float(((unsigned)u)<<16); }
__device__ inline ushort f2bf(float f){
  unsigned u = __float_as_uint(f);
  u += 0x7fffu + ((u>>16)&1u);          // RTNE
  return (ushort)(u>>16);
}

// fp32 -> bf16 convert, 8 elements per thread
__global__ __launch_bounds__(256) void cvt8(const float* __restrict__ in,
                                            ushort* __restrict__ out, int n8){
  int t = blockIdx.x*256 + threadIdx.x;
  if (t >= n8) return;
  const float4* p = (const float4*)(in + (size_t)t*8);
  float4 a = p[0], b = p[1];
  ushort r[8] = {f2bf(a.x),f2bf(a.y),f2bf(a.z),f2bf(a.w),
                 f2bf(b.x),f2bf(b.y),f2bf(b.z),f2bf(b.w)};
  *(uint4*)(out + (size_t)t*8) = *(const uint4*)r;
}

#define GLOAD(gp, lp) __builtin_amdgcn_global_load_lds( \
    (const __attribute__((address_space(1))) void*)(gp), \
    (__attribute__((address_space(3))) void*)(lp), 16, 0, 0)

// 128x256 tile, BK=32, 8 waves of 64x64, 48KB LDS -> 2 blocks/CU.
// Counted vmcnt: mid-tile VM(1) forces B(t); tile-end VM(2) forces A(t+1).
__global__ __launch_bounds__(512, 4) void gemm_sru(
    const ushort* __restrict__ gA,  // M x K bf16
    const ushort* __restrict__ gB,  // N x K bf16
    const float* __restrict__ bias, // N fp32
    ushort* __restrict__ xbuf, ushort* __restrict__ zbuf, ushort* __restrict__ hbuf)
{
  __shared__ ulong2 lds_[2*BUFB/16];   // 48 KiB
  char* ldsb = (char*)lds_;

  const int tid  = threadIdx.x;
  const int lane = tid & 63, w = tid >> 6;
  const int wm = w >> 2, wn = w & 3;          // 2x4 wave grid, 64x64 per wave
  const int l15 = lane & 15, l4 = lane >> 4;

  // XCD-chunked swizzle; nwg = 3072 (%8==0). Consecutive in-XCD blocks share B panel.
  const int bid = blockIdx.x;
  const int swz = (bid & 7)*384 + (bid >> 3);
  const int bnb = swz >> 8, bmb = swz & 255;  // 12 x 256
  const int bm = bmb*BM, bn = bnb*BN;

  // LDS layout: element (row,k): byte row*64 + ((k/8)^(row&3))*16 + (k%8)*2
  // read: lane row=base+l15 (base%4==0), k-slot=l>>4 -> pos=(l>>4)^(lane&3)
  const int offX = l15*64 + (((l4) ^ (lane&3))*16);
  const int offA = wm*4096 + offX;            // A region [0, 8192)
  const int offB = ABY + wn*4096 + offX;      // B region [8192, 24576)

  // staging: thread covers 16B chunk (row=tid>>2, pos=tid&3); inverse-swizzled source
  const int gsl = (tid & 3) ^ ((tid >> 2) & 3);
  const ushort* gAp = gA + (size_t)(bm + (tid>>2))*K_DIM + gsl*8;
  const ushort* gBp = gB + (size_t)(bn + (tid>>2))*K_DIM + gsl*8;

  f32x4 acc[4][4];
  #pragma unroll
  for (int i=0;i<4;i++)
    #pragma unroll
    for (int j=0;j<4;j++) acc[i][j] = (f32x4){0.f,0.f,0.f,0.f};

#define STAGE_A(tt) do{ \
    GLOAD(gAp + (tt)*BK, ldsb + ((tt)&1)*BUFB + tid*16); \
  }while(0)
#define STAGE_B(tt) do{ \
    GLOAD(gBp + (tt)*BK,                     ldsb + ((tt)&1)*BUFB + ABY + tid*16); \
    GLOAD(gBp + (size_t)128*K_DIM + (tt)*BK, ldsb + ((tt)&1)*BUFB + ABY + 8192 + tid*16); \
  }while(0)
#define BAR() asm volatile("" ::: "memory"); __builtin_amdgcn_s_barrier(); asm volatile("" ::: "memory")
#define VM(n) asm volatile("s_waitcnt vmcnt(" #n ")" ::: "memory")

  // prologue: stage tile 0 fully, drain, publish
  STAGE_A(0); STAGE_B(0);
  VM(0); BAR();

  // steady-state FIFO (3 gloads/tile): enter t with [Ba(t),Bb(t)] outstanding.
  //  +A(t+1) -> 3; VM(1) forces Ba,Bb (read after mid BAR), leaves [A'].
  //  +Ba',Bb' -> 3; VM(2) forces A' (read after end BAR). Never drains mid-loop.
  for (int t = 0; t < NKT; ++t) {
    const int bo = (t&1)*BUFB;
    bf16x8 af0 = *(const bf16x8*)(ldsb + bo + offA);
    bf16x8 af1 = *(const bf16x8*)(ldsb + bo + offA + 1024);
    bf16x8 af2 = *(const bf16x8*)(ldsb + bo + offA + 2048);
    bf16x8 af3 = *(const bf16x8*)(ldsb + bo + offA + 3072);
    if (t < NKT-1) { STAGE_A(t+1); VM(1); }
    else           { VM(0); }
    BAR();
    #pragma unroll
    for (int nt=0; nt<4; ++nt) {
      bf16x8 bfv = *(const bf16x8*)(ldsb + bo + offB + nt*1024);
      __builtin_amdgcn_s_setprio(1);
      acc[0][nt] = __builtin_amdgcn_mfma_f32_16x16x32_bf16(af0, bfv, acc[0][nt], 0,0,0);
      acc[1][nt] = __builtin_amdgcn_mfma_f32_16x16x32_bf16(af1, bfv, acc[1][nt], 0,0,0);
      acc[2][nt] = __builtin_amdgcn_mfma_f32_16x16x32_bf16(af2, bfv, acc[2][nt], 0,0,0);
      acc[3][nt] = __builtin_amdgcn_mfma_f32_16x16x32_bf16(af3, bfv, acc[3][nt], 0,0,0);
      __builtin_amdgcn_s_setprio(0);
    }
    if (t < NKT-1) { STAGE_B(t+1); VM(2); }
    BAR();
  }

  // ---- epilogue: two 32KB halves; acc -> LDS (bf16, bias+sigmoid, swizzled) -> coalesced ----
  const int region = bn >> 10;
  ushort* dst = region==0 ? xbuf : (region==1 ? zbuf : hbuf);
  const int cb = bn & (D_DIM-1);
  ushort* lds16 = (ushort*)ldsb;
  float bv[4];
  #pragma unroll
  for (int nt=0; nt<4; ++nt) bv[nt] = bias[bn + wn*64 + nt*16 + l15];

  #pragma unroll
  for (int h=0; h<2; ++h) {
    if (wm == h) {
      #pragma unroll
      for (int mt=0; mt<4; ++mt)
        #pragma unroll
        for (int nt=0; nt<4; ++nt)
          #pragma unroll
          for (int r=0; r<4; ++r) {
            int lrow = mt*16 + l4*4 + r;          // 0..63 within half
            int col  = wn*64 + nt*16 + l15;       // 0..255
            float v = acc[mt][nt][r] + bv[nt];
            if (region) v = 1.f/(1.f + __expf(-v));
            int slot = col >> 3;
            lds16[lrow*256 + (((slot ^ (lrow&31))&31)<<3) + (col&7)] = f2bf(v);
          }
    }
    __syncthreads();
    #pragma unroll
    for (int i=0; i<4; ++i) {
      int off = i*8192 + tid*16;                  // byte in 64x512B half-tile
      int lrow = off >> 9;
      int slot = (off >> 4) & 31;
      int dcol = (off & 511) >> 1;
      const char* src = ldsb + lrow*512 + (((slot ^ (lrow&31))&31)<<4);
      *(uint4*)(dst + (size_t)(bm + h*64 + lrow)*D_DIM + cb + dcol) = *(const uint4*)src;
    }
    __syncthreads();
  }
#undef STAGE_A
#undef STAGE_B
#undef BAR
#undef VM
}

// Pass 1: per (segment, 8-channel group) compose affine coefficients
__global__ __launch_bounds__(256) void scan_pass1(
    const ushort* __restrict__ z, const ushort* __restrict__ x,
    float* __restrict__ Aout, float* __restrict__ Bout)
{
  int t = blockIdx.x*256 + threadIdx.x;   // 0..131071
  int cg = t & (CG-1), g = t >> 11;       // CG = 2048 = 2^11
  int c0 = cg*8;
  size_t base = (size_t)g*SEGLEN*NCH + c0;
  float A[8], Bc[8];
  #pragma unroll
  for (int j=0;j<8;j++){ A[j]=1.f; Bc[j]=0.f; }
  #pragma unroll 4
  for (int i=0;i<SEGLEN;i++){
    uint4 zv = *(const uint4*)(z + base + (size_t)i*NCH);
    uint4 xv = *(const uint4*)(x + base + (size_t)i*NCH);
    const ushort* zp = (const ushort*)&zv;
    const ushort* xp = (const ushort*)&xv;
    #pragma unroll
    for (int j=0;j<8;j++){
      float zf = bf2f(zp[j]);
      float a  = 1.f - zf;
      float bb = zf * bf2f(xp[j]);
      Bc[j] = a*Bc[j] + bb;
      A[j]  = a*A[j];
    }
  }
  float* Ao = Aout + (size_t)g*NCH + c0;
  float* Bo = Bout + (size_t)g*NCH + c0;
  *(float4*)Ao     = make_float4(A[0],A[1],A[2],A[3]);
  *(float4*)(Ao+4) = make_float4(A[4],A[5],A[6],A[7]);
  *(float4*)Bo     = make_float4(Bc[0],Bc[1],Bc[2],Bc[3]);
  *(float4*)(Bo+4) = make_float4(Bc[4],Bc[5],Bc[6],Bc[7]);
}

// Pass 2: sequential scan over the 64 segment summaries per channel
__global__ __launch_bounds__(256) void scan_pass2(
    const float* __restrict__ A, const float* __restrict__ B,
    const float* __restrict__ h0, float* __restrict__ seg, float* __restrict__ hfin)
{
  int c = blockIdx.x*256 + threadIdx.x;   // 0..16383
  float s = h0[c];
  #pragma unroll 8
  for (int g=0; g<SEG; g++){
    seg[(size_t)g*NCH + c] = s;
    s = A[(size_t)g*NCH + c]*s + B[(size_t)g*NCH + c];
  }
  hfin[c] = s;
}

// Pass 3: replay each segment from its start state, fused output blend
__global__ __launch_bounds__(256) void scan_pass3(
    const ushort* __restrict__ z, const ushort* __restrict__ x, const ushort* __restrict__ hg,
    const float* __restrict__ prev, const float* __restrict__ seg,
    float* __restrict__ out)
{
  int t = blockIdx.x*256 + threadIdx.x;   // 0..131071
  int cg = t & (CG-1), g = t >> 11;
  int c0 = cg*8;
  float s[8];
  *(float4*)s     = *(const float4*)(seg + (size_t)g*NCH + c0);
  *(float4*)(s+4) = *(const float4*)(seg + (size_t)g*NCH + c0 + 4);
  size_t base = (size_t)g*SEGLEN*NCH + c0;
  #pragma unroll 2
  for (int i=0;i<SEGLEN;i++){
    size_t idx = base + (size_t)i*NCH;
    uint4 zv = *(const uint4*)(z+idx);
    uint4 xv = *(const uint4*)(x+idx);
    uint4 hv = *(const uint4*)(hg+idx);
    float4 p0 = *(const float4*)(prev+idx);
    float4 p1 = *(const float4*)(prev+idx+4);
    const ushort* zp=(const ushort*)&zv;
    const ushort* xp=(const ushort*)&xv;
    const ushort* hp=(const ushort*)&hv;
    float pv[8] = {p0.x,p0.y,p0.z,p0.w,p1.x,p1.y,p1.z,p1.w};
    float o[8];
    #pragma unroll
    for (int j=0;j<8;j++){
      float zf = bf2f(zp[j]);
      s[j] += zf*(bf2f(xp[j]) - s[j]);
      float hf = bf2f(hp[j]);
      o[j] = s[j] + hf*(pv[j] - s[j]);
    }
    *(float4*)(out+idx)   = make_float4(o[0],o[1],o[2],o[3]);
    *(float4*)(out+idx+4) = make_float4(o[4],o[5],o[6],o[7]);
  }
}

extern "C" void kernel_launch(void* const* d_in, const int* in_sizes, int n_in,
                              void* d_out, int out_size, void* d_ws, size_t ws_size,
                              hipStream_t stream) {
  const float* prev = (const float*)d_in[0];   // (L,B,D)
  const float* h0   = (const float*)d_in[1];   // (B,D)
  const float* W    = (const float*)d_in[2];   // (3D,D)
  const float* bias = (const float*)d_in[3];   // (3D,)
  float* out  = (float*)d_out;
  float* hfin = out + (size_t)M_DIM*D_DIM;

  char* ws = (char*)d_ws;
  ushort* Ab = (ushort*)ws;                                        // 64 MiB (dead after gemm)
  ushort* Wb = (ushort*)(ws + (size_t)M_DIM*K_DIM*2);              // 6 MiB
  ushort* xb = (ushort*)(ws + (size_t)M_DIM*K_DIM*2 + (size_t)N_DIM*K_DIM*2);
  ushort* zb = xb + (size_t)M_DIM*D_DIM;
  ushort* hb = zb + (size_t)M_DIM*D_DIM;
  // overlay scan scratch on Ab's region (only live after gemm completes)
  float* Abuf = (float*)ws;                     // SEG*NCH floats = 4 MiB
  float* Bbuf = Abuf + (size_t)SEG*NCH;         // 4 MiB
  float* segb = Bbuf + (size_t)SEG*NCH;         // 4 MiB

  cvt8<<<(M_DIM*K_DIM/8 + 255)/256, 256, 0, stream>>>(prev, Ab, M_DIM*K_DIM/8);
  cvt8<<<(N_DIM*K_DIM/8 + 255)/256, 256, 0, stream>>>(W,    Wb, N_DIM*K_DIM/8);
  gemm_sru<<<(M_DIM/BM)*(N_DIM/BN), 512, 0, stream>>>(Ab, Wb, bias, xb, zb, hb);
  scan_pass1<<<(CG*SEG)/256, 256, 0, stream>>>(zb, xb, Abuf, Bbuf);
  scan_pass2<<<NCH/256, 256, 0, stream>>>(Abuf, Bbuf, h0, segb, hfin);
  scan_pass3<<<(CG*SEG)/256, 256, 0, stream>>>(zb, xb, hb, prev, segb, out);
}

// Round 9
// 391.271 us; speedup vs baseline: 1.0282x; 1.0282x over previous
//
#include <hip/hip_runtime.h>
#include <cstdint>

#define L_DIM 2048
#define B_DIM 16
#define D_DIM 1024
#define M_DIM (L_DIM*B_DIM)   // 32768
#define N_DIM (3*D_DIM)       // 3072
#define K_DIM D_DIM           // 1024
#define NCH   (B_DIM*D_DIM)   // 16384 channels
#define SEG   64
#define SEGLEN (L_DIM/SEG)    // 32
#define CG    (NCH/8)         // 2048 channel-groups of 8

#define BK 64                 // K per tile-step
#define NKT (K_DIM/BK)        // 16 K-tiles
#define BUF 65536             // bytes per LDS buffer: A 32KB + B 32KB

typedef __bf16 bf16x8 __attribute__((ext_vector_type(8)));
typedef float f32x4 __attribute__((ext_vector_type(4)));

__device__ inline float bf2f(ushort u){ return __uint_as_float(((unsigned)u)<<16); }
__device__ inline ushort f2bf(float f){
  unsigned u = __float_as_uint(f);
  u += 0x7fffu + ((u>>16)&1u);          // RTNE
  return (ushort)(u>>16);
}

// fp32 -> bf16 convert, 8 elements per thread
__global__ __launch_bounds__(256) void cvt8(const float* __restrict__ in,
                                            ushort* __restrict__ out, int n8){
  int t = blockIdx.x*256 + threadIdx.x;
  if (t >= n8) return;
  const float4* p = (const float4*)(in + (size_t)t*8);
  float4 a = p[0], b = p[1];
  ushort r[8] = {f2bf(a.x),f2bf(a.y),f2bf(a.z),f2bf(a.w),
                 f2bf(b.x),f2bf(b.y),f2bf(b.z),f2bf(b.w)};
  *(uint4*)(out + (size_t)t*8) = *(const uint4*)r;
}

#define GLOAD(gp, lp) __builtin_amdgcn_global_load_lds( \
    (const __attribute__((address_space(1))) void*)(gp), \
    (__attribute__((address_space(3))) void*)(lp), 16, 0, 0)

// 256x256 tile, BK=64, 16 waves (4x4) of 64x64 each -> acc only 64 VGPR/wave.
// Simple 2-phase: stage(t+1) at tile top, one __syncthreads per tile.
__global__ __launch_bounds__(1024, 4) void gemm_sru(
    const ushort* __restrict__ gA,  // M x K bf16
    const ushort* __restrict__ gB,  // N x K bf16
    const float* __restrict__ bias, // N fp32
    ushort* __restrict__ xbuf, ushort* __restrict__ zbuf, ushort* __restrict__ hbuf)
{
  __shared__ ulong2 lds_[2*BUF/16];   // 128 KiB
  char* ldsb = (char*)lds_;

  const int tid  = threadIdx.x;
  const int lane = tid & 63, w = tid >> 6;
  const int wr = (w>>2)*64;            // wave row base (0..192)
  const int wc = (w&3)*64;             // wave col base (0..192)

  // XCD-chunked block swizzle (nwg=1536, %8==0 -> bijective)
  const int bid = blockIdx.x;
  const int swz = (bid & 7)*192 + (bid >> 3);
  const int bm = (swz / (N_DIM/256))*256, bn = (swz % (N_DIM/256))*256;

  // LDS: element (row,k): byte row*128 + ((k/8)^(row&7))*16 + (k%8)*2
  const int l15 = lane & 15, l4 = lane >> 4;
  const int s0 = ((l4)     ^ (l15&7)) * 16;   // k-slot group j=0
  const int s1 = ((4 + l4) ^ (l15&7)) * 16;   // k-slot group j=1
  const char* pA = ldsb + (wr + l15)*128;
  const char* pB = ldsb + 32768 + (wc + l15)*128;

  // staging: thread covers 16B; row = tid>>3 (+128 for 2nd gload), slot = tid&7
  const int gsl = (tid & 7) ^ ((tid >> 3) & 7);   // pre-swizzled global k-slot
  const ushort* gAp = gA + (size_t)(bm + (tid>>3))*K_DIM + gsl*8;
  const ushort* gBp = gB + (size_t)(bn + (tid>>3))*K_DIM + gsl*8;

  f32x4 acc[4][4];
  #pragma unroll
  for (int i=0;i<4;i++)
    #pragma unroll
    for (int j=0;j<4;j++) acc[i][j] = (f32x4){0.f,0.f,0.f,0.f};

#define STAGE(tt) do{ \
    char* d = ldsb + ((tt)&1)*BUF; \
    GLOAD(gAp + (size_t)(tt)*BK,                  d + tid*16); \
    GLOAD(gAp + (size_t)128*K_DIM + (size_t)(tt)*BK, d + 16384 + tid*16); \
    GLOAD(gBp + (size_t)(tt)*BK,                  d + 32768 + tid*16); \
    GLOAD(gBp + (size_t)128*K_DIM + (size_t)(tt)*BK, d + 49152 + tid*16); \
  }while(0)

  // prologue: stage tile 0, wait, publish
  STAGE(0);
  __syncthreads();   // drains vmcnt(0)+lgkmcnt(0) then barrier

  for (int t = 0; t < NKT; ++t) {
    const int bo = (t&1)*BUF;
    if (t < NKT-1) STAGE(t+1);      // writes other buffer; forced by tile-end syncthreads

    // j=0 k-slot group
    bf16x8 a0 = *(const bf16x8*)(pA + bo + 0*2048 + s0);
    bf16x8 a1 = *(const bf16x8*)(pA + bo + 1*2048 + s0);
    bf16x8 a2 = *(const bf16x8*)(pA + bo + 2*2048 + s0);
    bf16x8 a3 = *(const bf16x8*)(pA + bo + 3*2048 + s0);
    bf16x8 b0 = *(const bf16x8*)(pB + bo + 0*2048 + s0);
    bf16x8 b1 = *(const bf16x8*)(pB + bo + 1*2048 + s0);
    bf16x8 b2 = *(const bf16x8*)(pB + bo + 2*2048 + s0);
    bf16x8 b3 = *(const bf16x8*)(pB + bo + 3*2048 + s0);
    __builtin_amdgcn_s_setprio(1);
    acc[0][0] = __builtin_amdgcn_mfma_f32_16x16x32_bf16(a0, b0, acc[0][0], 0,0,0);
    acc[0][1] = __builtin_amdgcn_mfma_f32_16x16x32_bf16(a0, b1, acc[0][1], 0,0,0);
    acc[0][2] = __builtin_amdgcn_mfma_f32_16x16x32_bf16(a0, b2, acc[0][2], 0,0,0);
    acc[0][3] = __builtin_amdgcn_mfma_f32_16x16x32_bf16(a0, b3, acc[0][3], 0,0,0);
    acc[1][0] = __builtin_amdgcn_mfma_f32_16x16x32_bf16(a1, b0, acc[1][0], 0,0,0);
    acc[1][1] = __builtin_amdgcn_mfma_f32_16x16x32_bf16(a1, b1, acc[1][1], 0,0,0);
    acc[1][2] = __builtin_amdgcn_mfma_f32_16x16x32_bf16(a1, b2, acc[1][2], 0,0,0);
    acc[1][3] = __builtin_amdgcn_mfma_f32_16x16x32_bf16(a1, b3, acc[1][3], 0,0,0);
    acc[2][0] = __builtin_amdgcn_mfma_f32_16x16x32_bf16(a2, b0, acc[2][0], 0,0,0);
    acc[2][1] = __builtin_amdgcn_mfma_f32_16x16x32_bf16(a2, b1, acc[2][1], 0,0,0);
    acc[2][2] = __builtin_amdgcn_mfma_f32_16x16x32_bf16(a2, b2, acc[2][2], 0,0,0);
    acc[2][3] = __builtin_amdgcn_mfma_f32_16x16x32_bf16(a2, b3, acc[2][3], 0,0,0);
    acc[3][0] = __builtin_amdgcn_mfma_f32_16x16x32_bf16(a3, b0, acc[3][0], 0,0,0);
    acc[3][1] = __builtin_amdgcn_mfma_f32_16x16x32_bf16(a3, b1, acc[3][1], 0,0,0);
    acc[3][2] = __builtin_amdgcn_mfma_f32_16x16x32_bf16(a3, b2, acc[3][2], 0,0,0);
    acc[3][3] = __builtin_amdgcn_mfma_f32_16x16x32_bf16(a3, b3, acc[3][3], 0,0,0);
    __builtin_amdgcn_s_setprio(0);

    // j=1 k-slot group (reuse frag registers)
    a0 = *(const bf16x8*)(pA + bo + 0*2048 + s1);
    a1 = *(const bf16x8*)(pA + bo + 1*2048 + s1);
    a2 = *(const bf16x8*)(pA + bo + 2*2048 + s1);
    a3 = *(const bf16x8*)(pA + bo + 3*2048 + s1);
    b0 = *(const bf16x8*)(pB + bo + 0*2048 + s1);
    b1 = *(const bf16x8*)(pB + bo + 1*2048 + s1);
    b2 = *(const bf16x8*)(pB + bo + 2*2048 + s1);
    b3 = *(const bf16x8*)(pB + bo + 3*2048 + s1);
    __builtin_amdgcn_s_setprio(1);
    acc[0][0] = __builtin_amdgcn_mfma_f32_16x16x32_bf16(a0, b0, acc[0][0], 0,0,0);
    acc[0][1] = __builtin_amdgcn_mfma_f32_16x16x32_bf16(a0, b1, acc[0][1], 0,0,0);
    acc[0][2] = __builtin_amdgcn_mfma_f32_16x16x32_bf16(a0, b2, acc[0][2], 0,0,0);
    acc[0][3] = __builtin_amdgcn_mfma_f32_16x16x32_bf16(a0, b3, acc[0][3], 0,0,0);
    acc[1][0] = __builtin_amdgcn_mfma_f32_16x16x32_bf16(a1, b0, acc[1][0], 0,0,0);
    acc[1][1] = __builtin_amdgcn_mfma_f32_16x16x32_bf16(a1, b1, acc[1][1], 0,0,0);
    acc[1][2] = __builtin_amdgcn_mfma_f32_16x16x32_bf16(a1, b2, acc[1][2], 0,0,0);
    acc[1][3] = __builtin_amdgcn_mfma_f32_16x16x32_bf16(a1, b3, acc[1][3], 0,0,0);
    acc[2][0] = __builtin_amdgcn_mfma_f32_16x16x32_bf16(a2, b0, acc[2][0], 0,0,0);
    acc[2][1] = __builtin_amdgcn_mfma_f32_16x16x32_bf16(a2, b1, acc[2][1], 0,0,0);
    acc[2][2] = __builtin_amdgcn_mfma_f32_16x16x32_bf16(a2, b2, acc[2][2], 0,0,0);
    acc[2][3] = __builtin_amdgcn_mfma_f32_16x16x32_bf16(a2, b3, acc[2][3], 0,0,0);
    acc[3][0] = __builtin_amdgcn_mfma_f32_16x16x32_bf16(a3, b0, acc[3][0], 0,0,0);
    acc[3][1] = __builtin_amdgcn_mfma_f32_16x16x32_bf16(a3, b1, acc[3][1], 0,0,0);
    acc[3][2] = __builtin_amdgcn_mfma_f32_16x16x32_bf16(a3, b2, acc[3][2], 0,0,0);
    acc[3][3] = __builtin_amdgcn_mfma_f32_16x16x32_bf16(a3, b3, acc[3][3], 0,0,0);
    __builtin_amdgcn_s_setprio(0);

    __syncthreads();                // drains vmcnt (stage t+1 forced) + publishes
  }

  // ---- epilogue: acc -> LDS (bf16, bias+sigmoid, slot^row swizzle) -> coalesced ----
  const int region = bn >> 10;
  ushort* dst = region==0 ? xbuf : (region==1 ? zbuf : hbuf);
  ushort* lds16 = (ushort*)ldsb;
  float bv[4];
  #pragma unroll
  for (int g=0; g<4; ++g) bv[g] = bias[bn + wc + g*16 + l15];

  #pragma unroll
  for (int f=0; f<4; ++f)
    #pragma unroll
    for (int g=0; g<4; ++g)
      #pragma unroll
      for (int r=0; r<4; ++r){
        int row = wr + f*16 + l4*4 + r;
        int col = wc + g*16 + l15;
        float v = acc[f][g][r] + bv[g];
        if (region) v = 1.f/(1.f + __expf(-v));
        int slot = col >> 3;
        lds16[row*256 + (((slot ^ (row&31))&31)<<3) + (col&7)] = f2bf(v);
      }
  __syncthreads();
  const int cb = bn & (D_DIM-1);
  #pragma unroll
  for (int i=0;i<8;i++){
    int off = i*16384 + tid*16;               // byte in 256x512B tile
    int row = off >> 9;
    int slot = (off >> 4) & 31;
    int dcol = (off & 511) >> 1;
    const char* src = ldsb + row*512 + (((slot ^ (row&31))&31)<<4);
    *(uint4*)(dst + (size_t)(bm+row)*D_DIM + cb + dcol) = *(const uint4*)src;
  }
#undef STAGE
}

// Pass 1: per (segment, 8-channel group) compose affine coefficients
__global__ __launch_bounds__(256) void scan_pass1(
    const ushort* __restrict__ z, const ushort* __restrict__ x,
    float* __restrict__ Aout, float* __restrict__ Bout)
{
  int t = blockIdx.x*256 + threadIdx.x;   // 0..131071
  int cg = t & (CG-1), g = t >> 11;       // CG = 2048 = 2^11
  int c0 = cg*8;
  size_t base = (size_t)g*SEGLEN*NCH + c0;
  float A[8], Bc[8];
  #pragma unroll
  for (int j=0;j<8;j++){ A[j]=1.f; Bc[j]=0.f; }
  #pragma unroll 4
  for (int i=0;i<SEGLEN;i++){
    uint4 zv = *(const uint4*)(z + base + (size_t)i*NCH);
    uint4 xv = *(const uint4*)(x + base + (size_t)i*NCH);
    const ushort* zp = (const ushort*)&zv;
    const ushort* xp = (const ushort*)&xv;
    #pragma unroll
    for (int j=0;j<8;j++){
      float zf = bf2f(zp[j]);
      float a  = 1.f - zf;
      float bb = zf * bf2f(xp[j]);
      Bc[j] = a*Bc[j] + bb;
      A[j]  = a*A[j];
    }
  }
  float* Ao = Aout + (size_t)g*NCH + c0;
  float* Bo = Bout + (size_t)g*NCH + c0;
  *(float4*)Ao     = make_float4(A[0],A[1],A[2],A[3]);
  *(float4*)(Ao+4) = make_float4(A[4],A[5],A[6],A[7]);
  *(float4*)Bo     = make_float4(Bc[0],Bc[1],Bc[2],Bc[3]);
  *(float4*)(Bo+4) = make_float4(Bc[4],Bc[5],Bc[6],Bc[7]);
}

// Pass 2: sequential scan over the 64 segment summaries per channel
__global__ __launch_bounds__(256) void scan_pass2(
    const float* __restrict__ A, const float* __restrict__ B,
    const float* __restrict__ h0, float* __restrict__ seg, float* __restrict__ hfin)
{
  int c = blockIdx.x*256 + threadIdx.x;   // 0..16383
  float s = h0[c];
  #pragma unroll 8
  for (int g=0; g<SEG; g++){
    seg[(size_t)g*NCH + c] = s;
    s = A[(size_t)g*NCH + c]*s + B[(size_t)g*NCH + c];
  }
  hfin[c] = s;
}

// Pass 3: replay each segment from its start state, fused output blend
__global__ __launch_bounds__(256) void scan_pass3(
    const ushort* __restrict__ z, const ushort* __restrict__ x, const ushort* __restrict__ hg,
    const float* __restrict__ prev, const float* __restrict__ seg,
    float* __restrict__ out)
{
  int t = blockIdx.x*256 + threadIdx.x;   // 0..131071
  int cg = t & (CG-1), g = t >> 11;
  int c0 = cg*8;
  float s[8];
  *(float4*)s     = *(const float4*)(seg + (size_t)g*NCH + c0);
  *(float4*)(s+4) = *(const float4*)(seg + (size_t)g*NCH + c0 + 4);
  size_t base = (size_t)g*SEGLEN*NCH + c0;
  #pragma unroll 2
  for (int i=0;i<SEGLEN;i++){
    size_t idx = base + (size_t)i*NCH;
    uint4 zv = *(const uint4*)(z+idx);
    uint4 xv = *(const uint4*)(x+idx);
    uint4 hv = *(const uint4*)(hg+idx);
    float4 p0 = *(const float4*)(prev+idx);
    float4 p1 = *(const float4*)(prev+idx+4);
    const ushort* zp=(const ushort*)&zv;
    const ushort* xp=(const ushort*)&xv;
    const ushort* hp=(const ushort*)&hv;
    float pv[8] = {p0.x,p0.y,p0.z,p0.w,p1.x,p1.y,p1.z,p1.w};
    float o[8];
    #pragma unroll
    for (int j=0;j<8;j++){
      float zf = bf2f(zp[j]);
      s[j] += zf*(bf2f(xp[j]) - s[j]);
      float hf = bf2f(hp[j]);
      o[j] = s[j] + hf*(pv[j] - s[j]);
    }
    *(float4*)(out+idx)   = make_float4(o[0],o[1],o[2],o[3]);
    *(float4*)(out+idx+4) = make_float4(o[4],o[5],o[6],o[7]);
  }
}

extern "C" void kernel_launch(void* const* d_in, const int* in_sizes, int n_in,
                              void* d_out, int out_size, void* d_ws, size_t ws_size,
                              hipStream_t stream) {
  const float* prev = (const float*)d_in[0];   // (L,B,D)
  const float* h0   = (const float*)d_in[1];   // (B,D)
  const float* W    = (const float*)d_in[2];   // (3D,D)
  const float* bias = (const float*)d_in[3];   // (3D,)
  float* out  = (float*)d_out;
  float* hfin = out + (size_t)M_DIM*D_DIM;

  char* ws = (char*)d_ws;
  ushort* Ab = (ushort*)ws;                                        // 64 MiB (dead after gemm)
  ushort* Wb = (ushort*)(ws + (size_t)M_DIM*K_DIM*2);              // 6 MiB
  ushort* xb = (ushort*)(ws + (size_t)M_DIM*K_DIM*2 + (size_t)N_DIM*K_DIM*2);
  ushort* zb = xb + (size_t)M_DIM*D_DIM;
  ushort* hb = zb + (size_t)M_DIM*D_DIM;
  // overlay scan scratch on Ab's region (only live after gemm completes)
  float* Abuf = (float*)ws;                     // SEG*NCH floats = 4 MiB
  float* Bbuf = Abuf + (size_t)SEG*NCH;         // 4 MiB
  float* segb = Bbuf + (size_t)SEG*NCH;         // 4 MiB

  cvt8<<<(M_DIM*K_DIM/8 + 255)/256, 256, 0, stream>>>(prev, Ab, M_DIM*K_DIM/8);
  cvt8<<<(N_DIM*K_DIM/8 + 255)/256, 256, 0, stream>>>(W,    Wb, N_DIM*K_DIM/8);
  gemm_sru<<<(M_DIM/256)*(N_DIM/256), 1024, 0, stream>>>(Ab, Wb, bias, xb, zb, hb);
  scan_pass1<<<(CG*SEG)/256, 256, 0, stream>>>(zb, xb, Abuf, Bbuf);
  scan_pass2<<<NCH/256, 256, 0, stream>>>(Abuf, Bbuf, h0, segb, hfin);
  scan_pass3<<<(CG*SEG)/256, 256, 0, stream>>>(zb, xb, hb, prev, segb, out);
}